// Round 2
// baseline (647.898 us; speedup 1.0000x reference)
//
#include <hip/hip_runtime.h>
#include <hip/hip_bf16.h>
#include <math.h>

// Fused SparseNet: conv1(2x2,200->16,pad(0,1)) via bf16 MFMA + masked pool 3x3/3
// + conv2(5x5,16->32) + masked pool 3x3/1 + linear(32,2) + softmax.
// One block per batch element. B=1024.

typedef short short8 __attribute__((ext_vector_type(8)));
typedef float f32x4 __attribute__((ext_vector_type(4)));

#define NEGINF -1e30f
#define XSTR 40            // bf16 elems per LDS row: 32 data + 8 pad (80 B, keeps b128 aligned, ~2-way banks = free)
#define CELLS 506          // 23 rows x 22 cols: 21x21 real + zero pad row/col + overflow row for M-padding garbage

static __device__ __forceinline__ unsigned short f2bf(float f) {
    return __builtin_bit_cast(unsigned short, __float2bfloat16(f));
}

__global__ __launch_bounds__(256) void fused_sparse_net(
    const float* __restrict__ x,     // [1024,21,21,200]
    const int*   __restrict__ mask,  // [1024,21,21]
    const float* __restrict__ W1,    // [2,2,200,16]
    const float* __restrict__ W2,    // [5,5,16,32]
    const float* __restrict__ Wlin,  // [32,2]
    const float* __restrict__ blin,  // [2]
    float* __restrict__ out)         // [1024,2]
{
    __shared__ unsigned short xm[CELLS * XSTR];     // 40,480 B  (masked x chunk, bf16; later overlaid by h1s)
    __shared__ unsigned short ws[4 * 16 * XSTR];    //  5,120 B  (W1 chunk as B-frags: [tap][n][k])
    __shared__ int   mb_s[441];
    __shared__ float h2s[49][16];
    __shared__ float m2s[49];
    __shared__ float hcs[9][32];
    __shared__ float m3s[9];
    __shared__ float h4s[32];

    const int b    = blockIdx.x;
    const int t    = threadIdx.x;
    const int lane = t & 63;
    const int wave = t >> 6;
    const int mrow = lane & 15;   // MFMA A-row / B-col index
    const int kq   = lane >> 4;   // MFMA k-quad

    const float* __restrict__ xb = x + (size_t)b * 88200;
    const int*   __restrict__ mb = mask + b * 441;

    for (int p = t; p < 441; p += 256) mb_s[p] = mb[p];

    // zero the geometric pad cells once (row 21 + col 21): conv pad (0,1) AND mask-zero semantics
    for (int q = t; q < 172; q += 256) {
        int pc = q >> 2, seg = q & 3;
        int cell = (pc < 22) ? (462 + pc) : ((pc - 22) * 22 + 21);
        short8 z = {0, 0, 0, 0, 0, 0, 0, 0};
        *(short8*)&xm[cell * XSTR + seg * 8] = z;
    }

    // per-tile base cell for this lane's A-row (output pixel). p up to 447; rows >= 441 are
    // discarded garbage (their reads stay inside the 506-row allocation).
    int cell0[7];
    #pragma unroll
    for (int tile = 0; tile < 7; ++tile) {
        int p = (wave * 7 + tile) * 16 + mrow;
        int i = p / 21;
        cell0[tile] = i * 22 + (p - i * 21);
    }

    f32x4 acc[7];
    #pragma unroll
    for (int tile = 0; tile < 7; ++tile) acc[tile] = (f32x4){0.f, 0.f, 0.f, 0.f};

    // ---- conv1: K = 4 taps x 224 (200 real channels + zero pad), chunks of 32 ----
    for (int ch = 0; ch < 7; ++ch) {
        __syncthreads();   // previous chunk's MFMA reads done before LDS overwrite

        // stage W1 chunk -> ws[tap][n][k] (bf16, transposed for contiguous B-frag reads)
        for (int idx = t; idx < 2048; idx += 256) {
            int tap = idx >> 9, rem = idx & 511;
            int k = rem >> 4, n = rem & 15;
            int c = ch * 32 + k;
            float w = (c < 200) ? W1[(tap * 200 + c) * 16 + n] : 0.f;
            ws[(tap * 16 + n) * XSTR + k] = f2bf(w);
        }

        // stage masked x chunk -> xm[cell][k]; skip HBM loads at inactive pixels.
        // chunk 6 has only 8 real channels (seg 0); segs 1..3 stay stale but B is zero there.
        const int niter = (ch < 6) ? 1764 : 441;
        for (int idx = t; idx < niter; idx += 256) {
            int pixel, seg;
            if (ch < 6) { pixel = idx >> 2; seg = idx & 3; }
            else        { pixel = idx;      seg = 0;       }
            int i = pixel / 21;
            int cell = i * 22 + (pixel - i * 21);
            unsigned short* dst = &xm[cell * XSTR + seg * 8];
            if (mb_s[pixel] != 0) {
                const float4* src = (const float4*)(xb + pixel * 200 + ch * 32 + seg * 8);
                float4 a0 = src[0];
                float4 a1 = src[1];
                short8 v;
                v[0] = (short)f2bf(a0.x); v[1] = (short)f2bf(a0.y);
                v[2] = (short)f2bf(a0.z); v[3] = (short)f2bf(a0.w);
                v[4] = (short)f2bf(a1.x); v[5] = (short)f2bf(a1.y);
                v[6] = (short)f2bf(a1.z); v[7] = (short)f2bf(a1.w);
                *(short8*)dst = v;
            } else {
                short8 z = {0, 0, 0, 0, 0, 0, 0, 0};
                *(short8*)dst = z;
            }
        }
        __syncthreads();

        // B-frags for the 4 taps (one per wave, reused across all 7 M-tiles)
        short8 bfrag[4];
        #pragma unroll
        for (int tap = 0; tap < 4; ++tap)
            bfrag[tap] = *(const short8*)&ws[(tap * 16 + mrow) * XSTR + kq * 8];

        // MFMA sweep: all 4 taps read the SAME x tile at shifted cells
        #pragma unroll
        for (int tile = 0; tile < 7; ++tile) {
            #pragma unroll
            for (int tap = 0; tap < 4; ++tap) {
                int cell = cell0[tile] + (tap >> 1) * 22 + (tap & 1);
                short8 afrag = *(const short8*)&xm[cell * XSTR + kq * 8];
                acc[tile] = __builtin_amdgcn_mfma_f32_16x16x32_bf16(
                    afrag, bfrag[tap], acc[tile], 0, 0, 0);
            }
        }
    }

    __syncthreads();   // conv1 LDS reads done; overlay h1 on xm region

    float (*h1s)[17] = (float (*)[17])(void*)xm;   // 441*17*4 = 29,988 B <= 40,480
    #pragma unroll
    for (int tile = 0; tile < 7; ++tile) {
        #pragma unroll
        for (int r = 0; r < 4; ++r) {
            int p = (wave * 7 + tile) * 16 + kq * 4 + r;   // C/D: row=(lane>>4)*4+reg, col=lane&15
            if (p < 441) h1s[p][mrow] = acc[tile][r];
        }
    }
    __syncthreads();

    // ---- masked maxpool 3x3/3: 21 -> 7 (inactive h1 sites never read) ----
    for (int t2 = t; t2 < 784; t2 += 256) {
        int cell = t2 >> 4, c = t2 & 15;
        int pr = cell / 7, pc = cell - pr * 7;
        float best = NEGINF;
        bool any = false;
        #pragma unroll
        for (int r = 0; r < 3; ++r) {
            #pragma unroll
            for (int cc = 0; cc < 3; ++cc) {
                int s = (pr * 3 + r) * 21 + (pc * 3 + cc);
                if (mb_s[s] != 0) { any = true; best = fmaxf(best, h1s[s][c]); }
            }
        }
        h2s[cell][c] = any ? best : 0.0f;
        if (c == 0) m2s[cell] = any ? 1.0f : 0.0f;
    }
    __syncthreads();

    // ---- conv2 5x5 VALID: 7 -> 3, 16 -> 32ch, gated by 5x5 mask-pool ----
    for (int t2 = t; t2 < 288; t2 += 256) {
        int cell = t2 >> 5, oc = t2 & 31;
        int ci = cell / 3, cj = cell - ci * 3;
        float a2 = 0.f, mm = 0.f;
        #pragma unroll
        for (int di = 0; di < 5; ++di) {
            #pragma unroll
            for (int dj = 0; dj < 5; ++dj) {
                int s = (ci + di) * 7 + (cj + dj);
                mm = fmaxf(mm, m2s[s]);
                const float* __restrict__ wp2 = W2 + ((di * 5 + dj) * 16) * 32 + oc;
                const float4* hv = (const float4*)&h2s[s][0];
                float4 h0 = hv[0], h1v = hv[1], h2v = hv[2], h3v = hv[3];
                a2 = fmaf(h0.x,  wp2[0 * 32],  a2);
                a2 = fmaf(h0.y,  wp2[1 * 32],  a2);
                a2 = fmaf(h0.z,  wp2[2 * 32],  a2);
                a2 = fmaf(h0.w,  wp2[3 * 32],  a2);
                a2 = fmaf(h1v.x, wp2[4 * 32],  a2);
                a2 = fmaf(h1v.y, wp2[5 * 32],  a2);
                a2 = fmaf(h1v.z, wp2[6 * 32],  a2);
                a2 = fmaf(h1v.w, wp2[7 * 32],  a2);
                a2 = fmaf(h2v.x, wp2[8 * 32],  a2);
                a2 = fmaf(h2v.y, wp2[9 * 32],  a2);
                a2 = fmaf(h2v.z, wp2[10 * 32], a2);
                a2 = fmaf(h2v.w, wp2[11 * 32], a2);
                a2 = fmaf(h3v.x, wp2[12 * 32], a2);
                a2 = fmaf(h3v.y, wp2[13 * 32], a2);
                a2 = fmaf(h3v.z, wp2[14 * 32], a2);
                a2 = fmaf(h3v.w, wp2[15 * 32], a2);
            }
        }
        hcs[cell][oc] = (mm > 0.f) ? a2 : 0.f;
        if (oc == 0) m3s[cell] = mm;
    }
    __syncthreads();

    // ---- final masked pool 3x3/1 on 3x3 -> 1x1 ----
    if (t < 32) {
        float best = NEGINF;
        bool any = false;
        #pragma unroll
        for (int cell = 0; cell < 9; ++cell) {
            if (m3s[cell] > 0.f) { any = true; best = fmaxf(best, hcs[cell][t]); }
        }
        h4s[t] = any ? best : 0.f;
    }
    __syncthreads();

    // ---- linear(32,2) + softmax ----
    if (t == 0) {
        float l0 = blin[0], l1 = blin[1];
        #pragma unroll
        for (int c = 0; c < 32; ++c) {
            l0 = fmaf(h4s[c], Wlin[c * 2 + 0], l0);
            l1 = fmaf(h4s[c], Wlin[c * 2 + 1], l1);
        }
        float mx = fmaxf(l0, l1);
        float e0 = expf(l0 - mx);
        float e1 = expf(l1 - mx);
        float inv = 1.f / (e0 + e1);
        out[b * 2 + 0] = e0 * inv;
        out[b * 2 + 1] = e1 * inv;
    }
}

extern "C" void kernel_launch(void* const* d_in, const int* in_sizes, int n_in,
                              void* d_out, int out_size, void* d_ws, size_t ws_size,
                              hipStream_t stream) {
    const float* x    = (const float*)d_in[0];
    const int*   mask = (const int*)d_in[1];
    const float* W1   = (const float*)d_in[2];
    const float* W2   = (const float*)d_in[3];
    const float* Wlin = (const float*)d_in[4];
    const float* blin = (const float*)d_in[5];
    float* out = (float*)d_out;

    fused_sparse_net<<<1024, 256, 0, stream>>>(x, mask, W1, W2, Wlin, blin, out);
}